// Round 2
// baseline (961.650 us; speedup 1.0000x reference)
//
#include <hip/hip_runtime.h>

#define TS 1000

__device__ __forceinline__ float rl(float v, int lane) {
    return __int_as_float(__builtin_amdgcn_readlane(__float_as_int(v), lane));
}
__device__ __forceinline__ float fsig(float x) {
    return __builtin_amdgcn_rcpf(1.0f + __expf(-x));
}
__device__ __forceinline__ float ftanh(float x) {
    return 1.0f - 2.0f * __builtin_amdgcn_rcpf(1.0f + __expf(2.0f * x));
}

// ---------------- Phase 1: gx[g][b][t][192] = x[b][t][g*64..] @ W[g] + b_i[g]
// grid (16 t-tiles, 32 b, 8 g), 256 threads. Standard LDS-staged GEMM.
__global__ __launch_bounds__(256)
void gx_gemm(const float* __restrict__ x, const float* __restrict__ W,
             const float* __restrict__ bi, float* __restrict__ gx)
{
    const int g = blockIdx.z, b = blockIdx.y, t0 = blockIdx.x * 64;
    const int rows = (TS - t0 < 64) ? (TS - t0) : 64;

    __shared__ float xt[64][64];
    const float* xrow = x + (size_t)b * (TS * 512) + g * 64;
    for (int idx = threadIdx.x; idx < 64 * 64; idx += 256) {
        const int r = idx >> 6, k = idx & 63;
        const int t = t0 + ((r < rows) ? r : (rows - 1));
        xt[r][k] = xrow[(size_t)t * 512 + k];
    }
    __syncthreads();

    const int tr = threadIdx.x >> 6, tc = threadIdx.x & 63;
    float acc[16][3];
    {
        const float b0 = bi[g * 192 + tc], b1 = bi[g * 192 + 64 + tc], b2 = bi[g * 192 + 128 + tc];
        #pragma unroll
        for (int i = 0; i < 16; ++i) { acc[i][0] = b0; acc[i][1] = b1; acc[i][2] = b2; }
    }
    const float* Wg = W + (size_t)g * (64 * 192);
    #pragma unroll 4
    for (int k = 0; k < 64; ++k) {
        const float w0 = Wg[k * 192 + tc];
        const float w1 = Wg[k * 192 + 64 + tc];
        const float w2 = Wg[k * 192 + 128 + tc];
        #pragma unroll
        for (int i = 0; i < 16; ++i) {
            const float xv = xt[tr * 16 + i][k];   // uniform per wave -> LDS broadcast
            acc[i][0] = fmaf(xv, w0, acc[i][0]);
            acc[i][1] = fmaf(xv, w1, acc[i][1]);
            acc[i][2] = fmaf(xv, w2, acc[i][2]);
        }
    }
    float* gp = gx + ((size_t)(g * 32 + b) * TS + t0) * 192;
    #pragma unroll
    for (int i = 0; i < 16; ++i) {
        const int r = tr * 16 + i;
        if (r < rows) {
            gp[(size_t)r * 192 + tc]       = acc[i][0];
            gp[(size_t)r * 192 + 64 + tc]  = acc[i][1];
            gp[(size_t)r * 192 + 128 + tc] = acc[i][2];
        }
    }
}

// ---------------- Phase 2: serial recurrence. ONE wave per (g,b) chain.
// No LDS, no barriers. U stationary in VGPRs, h broadcast via readlane.
__global__ __launch_bounds__(64, 1)
void gru_seq(const float* __restrict__ gx, const float* __restrict__ h0,
             const float* __restrict__ U, const float* __restrict__ bh,
             float* __restrict__ out, float* __restrict__ hout)
{
    const int g = blockIdx.x >> 5, b = blockIdx.x & 31;
    const int lane = threadIdx.x;

    float u[64][3];
    {
        const float* Ug = U + (size_t)g * (64 * 192) + lane;
        #pragma unroll
        for (int k = 0; k < 64; ++k) {
            u[k][0] = Ug[k * 192];
            u[k][1] = Ug[k * 192 + 64];
            u[k][2] = Ug[k * 192 + 128];
        }
    }
    const float bz = bh[g * 192 + lane];
    const float br = bh[g * 192 + 64 + lane];
    const float bn = bh[g * 192 + 128 + lane];

    float h = h0[(g * 32 + b) * 64 + lane];

    const float* gp = gx + (size_t)(g * 32 + b) * (TS * 192);
    float cz  = gp[lane],        crr = gp[64 + lane],  cn  = gp[128 + lane];
    float n1z = gp[192 + lane],  n1r = gp[256 + lane], n1n = gp[320 + lane];
    float n2z, n2r, n2n;

    float* op = out + (size_t)b * (TS * 512) + g * 64 + lane;

    for (int t = 0; t < TS; ++t) {
        // prefetch gx(t+2)
        {
            const int tp = (t + 2 < TS) ? (t + 2) : (TS - 1);
            const float* pp = gp + (size_t)tp * 192;
            n2z = pp[lane]; n2r = pp[64 + lane]; n2n = pp[128 + lane];
        }
        float az = bz, ar = br, an = bn;
        #pragma unroll
        for (int k = 0; k < 64; ++k) {
            const float s = rl(h, k);
            az = fmaf(s, u[k][0], az);
            ar = fmaf(s, u[k][1], ar);
            an = fmaf(s, u[k][2], an);
        }
        const float z = fsig(cz + az);
        const float r = fsig(crr + ar);
        const float n = ftanh(fmaf(r, an, cn));   // reset_after: r * (h@U_n + b_h_n)
        h = n + z * (h - n);
        op[(size_t)t * 512] = h;

        cz = n1z; crr = n1r; cn = n1n;
        n1z = n2z; n1r = n2r; n1n = n2n;
    }
    hout[(g * 32 + b) * 64 + lane] = h;
}

// ---------------- Fallback (ws too small): fused single-wave, both matmuls inline.
__global__ __launch_bounds__(64, 1)
void gru_fused1(const float* __restrict__ x, const float* __restrict__ h0,
                const float* __restrict__ W, const float* __restrict__ U,
                const float* __restrict__ bi, const float* __restrict__ bh,
                float* __restrict__ out, float* __restrict__ hout)
{
    const int g = blockIdx.x >> 5, b = blockIdx.x & 31;
    const int lane = threadIdx.x;

    float u[64][3], w[64][3];
    {
        const float* Ug = U + (size_t)g * (64 * 192) + lane;
        const float* Wg = W + (size_t)g * (64 * 192) + lane;
        #pragma unroll
        for (int k = 0; k < 64; ++k) {
            u[k][0] = Ug[k * 192]; u[k][1] = Ug[k * 192 + 64]; u[k][2] = Ug[k * 192 + 128];
            w[k][0] = Wg[k * 192]; w[k][1] = Wg[k * 192 + 64]; w[k][2] = Wg[k * 192 + 128];
        }
    }
    const float biz = bi[g * 192 + lane], bir = bi[g * 192 + 64 + lane], bin_ = bi[g * 192 + 128 + lane];
    const float bhz = bh[g * 192 + lane], bhr = bh[g * 192 + 64 + lane], bhn = bh[g * 192 + 128 + lane];

    float h = h0[(g * 32 + b) * 64 + lane];
    const float* xp = x + (size_t)b * (TS * 512) + g * 64 + lane;
    float xc = xp[0], x1 = xp[512], x2;

    float* op = out + (size_t)b * (TS * 512) + g * 64 + lane;

    for (int t = 0; t < TS; ++t) {
        {
            const int tp = (t + 2 < TS) ? (t + 2) : (TS - 1);
            x2 = xp[(size_t)tp * 512];
        }
        float axz = biz, axr = bir, axn = bin_;
        float ahz = bhz, ahr = bhr, ahn = bhn;
        #pragma unroll
        for (int k = 0; k < 64; ++k) {
            const float sx = rl(xc, k);
            axz = fmaf(sx, w[k][0], axz);
            axr = fmaf(sx, w[k][1], axr);
            axn = fmaf(sx, w[k][2], axn);
        }
        #pragma unroll
        for (int k = 0; k < 64; ++k) {
            const float sh = rl(h, k);
            ahz = fmaf(sh, u[k][0], ahz);
            ahr = fmaf(sh, u[k][1], ahr);
            ahn = fmaf(sh, u[k][2], ahn);
        }
        const float z = fsig(axz + ahz);
        const float r = fsig(axr + ahr);
        const float n = ftanh(fmaf(r, ahn, axn));
        h = n + z * (h - n);
        op[(size_t)t * 512] = h;
        xc = x1; x1 = x2;
    }
    hout[(g * 32 + b) * 64 + lane] = h;
}

extern "C" void kernel_launch(void* const* d_in, const int* in_sizes, int n_in,
                              void* d_out, int out_size, void* d_ws, size_t ws_size,
                              hipStream_t stream) {
    const float* x  = (const float*)d_in[0];
    const float* h0 = (const float*)d_in[1];
    const float* W  = (const float*)d_in[2];
    const float* U  = (const float*)d_in[3];
    const float* bi = (const float*)d_in[4];
    const float* bh = (const float*)d_in[5];
    float* out  = (float*)d_out;
    float* hout = out + (size_t)32 * TS * 512;

    const size_t gx_bytes = (size_t)8 * 32 * TS * 192 * sizeof(float);
    if (ws_size >= gx_bytes) {
        float* gx = (float*)d_ws;
        hipLaunchKernelGGL(gx_gemm, dim3(16, 32, 8), dim3(256), 0, stream, x, W, bi, gx);
        hipLaunchKernelGGL(gru_seq, dim3(256), dim3(64), 0, stream, gx, h0, U, bh, out, hout);
    } else {
        hipLaunchKernelGGL(gru_fused1, dim3(256), dim3(64), 0, stream,
                           x, h0, W, U, bi, bh, out, hout);
    }
}

// Round 3
// 941.925 us; speedup vs baseline: 1.0209x; 1.0209x over previous
//
#include <hip/hip_runtime.h>

#define TS 1000

__device__ __forceinline__ float rl(float v, int lane) {
    return __int_as_float(__builtin_amdgcn_readlane(__float_as_int(v), lane));
}
__device__ __forceinline__ float fsig(float x) {
    return __builtin_amdgcn_rcpf(1.0f + __expf(-x));
}
__device__ __forceinline__ float ftanh(float x) {
    return 1.0f - 2.0f * __builtin_amdgcn_rcpf(1.0f + __expf(2.0f * x));
}

// ---------------- Phase 1: gx[g][b][t][192] = x[b][t][g*64..] @ W[g] + b_i[g]
// grid (16 t-tiles, 32 b, 8 g), 256 threads. Standard LDS-staged GEMM.
// (unchanged from round 2 — known good, ~189 us)
__global__ __launch_bounds__(256)
void gx_gemm(const float* __restrict__ x, const float* __restrict__ W,
             const float* __restrict__ bi, float* __restrict__ gx)
{
    const int g = blockIdx.z, b = blockIdx.y, t0 = blockIdx.x * 64;
    const int rows = (TS - t0 < 64) ? (TS - t0) : 64;

    __shared__ float xt[64][64];
    const float* xrow = x + (size_t)b * (TS * 512) + g * 64;
    for (int idx = threadIdx.x; idx < 64 * 64; idx += 256) {
        const int r = idx >> 6, k = idx & 63;
        const int t = t0 + ((r < rows) ? r : (rows - 1));
        xt[r][k] = xrow[(size_t)t * 512 + k];
    }
    __syncthreads();

    const int tr = threadIdx.x >> 6, tc = threadIdx.x & 63;
    float acc[16][3];
    {
        const float b0 = bi[g * 192 + tc], b1 = bi[g * 192 + 64 + tc], b2 = bi[g * 192 + 128 + tc];
        #pragma unroll
        for (int i = 0; i < 16; ++i) { acc[i][0] = b0; acc[i][1] = b1; acc[i][2] = b2; }
    }
    const float* Wg = W + (size_t)g * (64 * 192);
    #pragma unroll 4
    for (int k = 0; k < 64; ++k) {
        const float w0 = Wg[k * 192 + tc];
        const float w1 = Wg[k * 192 + 64 + tc];
        const float w2 = Wg[k * 192 + 128 + tc];
        #pragma unroll
        for (int i = 0; i < 16; ++i) {
            const float xv = xt[tr * 16 + i][k];   // uniform per wave -> LDS broadcast
            acc[i][0] = fmaf(xv, w0, acc[i][0]);
            acc[i][1] = fmaf(xv, w1, acc[i][1]);
            acc[i][2] = fmaf(xv, w2, acc[i][2]);
        }
    }
    float* gp = gx + ((size_t)(g * 32 + b) * TS + t0) * 192;
    #pragma unroll
    for (int i = 0; i < 16; ++i) {
        const int r = tr * 16 + i;
        if (r < rows) {
            gp[(size_t)r * 192 + tc]       = acc[i][0];
            gp[(size_t)r * 192 + 64 + tc]  = acc[i][1];
            gp[(size_t)r * 192 + 128 + tc] = acc[i][2];
        }
    }
}

// ---------------- Phase 2: serial recurrence. ONE wave per (g,b) chain.
// No LDS, no barriers, bitwise deterministic. U stationary in VGPRs —
// the empty-asm "+v" pin makes each loaded weight an asm-defined value so
// LLVM cannot rematerialize (re-load) it inside the t-loop. 512-VGPR budget
// at 1 wave/EU; ~230 needed.
__global__ __launch_bounds__(64, 1)
void gru_seq(const float* __restrict__ gx, const float* __restrict__ h0,
             const float* __restrict__ U, const float* __restrict__ bh,
             float* __restrict__ out, float* __restrict__ hout)
{
    const int g = blockIdx.x >> 5, b = blockIdx.x & 31;
    const int lane = threadIdx.x;

    float u0[64], u1[64], u2[64];
    {
        const float* Ug = U + (size_t)g * (64 * 192) + lane;
        #pragma unroll
        for (int k = 0; k < 64; ++k) {
            u0[k] = Ug[k * 192];
            u1[k] = Ug[k * 192 + 64];
            u2[k] = Ug[k * 192 + 128];
        }
    }
    // Pin: forces all 192 weights to live in VGPRs across the whole t-loop.
    #pragma unroll
    for (int k = 0; k < 64; ++k)
        asm volatile("" : "+v"(u0[k]), "+v"(u1[k]), "+v"(u2[k]));

    const float bz = bh[g * 192 + lane];
    const float br = bh[g * 192 + 64 + lane];
    const float bn = bh[g * 192 + 128 + lane];

    float h = h0[(g * 32 + b) * 64 + lane];

    const float* gp = gx + (size_t)(g * 32 + b) * (TS * 192);
    float cz  = gp[lane],        crr = gp[64 + lane],  cn  = gp[128 + lane];
    float n1z = gp[192 + lane],  n1r = gp[256 + lane], n1n = gp[320 + lane];
    float n2z, n2r, n2n;

    float* op = out + (size_t)b * (TS * 512) + g * 64 + lane;

    for (int t = 0; t < TS; ++t) {
        // prefetch gx(t+2)
        {
            const int tp = (t + 2 < TS) ? (t + 2) : (TS - 1);
            const float* pp = gp + (size_t)tp * 192;
            n2z = pp[lane]; n2r = pp[64 + lane]; n2n = pp[128 + lane];
        }
        float az = bz, ar = br, an = bn;
        #pragma unroll
        for (int k = 0; k < 64; ++k) {
            const float s = rl(h, k);
            az = fmaf(s, u0[k], az);
            ar = fmaf(s, u1[k], ar);
            an = fmaf(s, u2[k], an);
        }
        const float z = fsig(cz + az);
        const float r = fsig(crr + ar);
        const float n = ftanh(fmaf(r, an, cn));   // reset_after: r * (h@U_n + b_h_n)
        h = n + z * (h - n);
        op[(size_t)t * 512] = h;

        cz = n1z; crr = n1r; cn = n1n;
        n1z = n2z; n1r = n2r; n1n = n2n;
    }
    hout[(g * 32 + b) * 64 + lane] = h;
}

// ---------------- Fallback (ws too small): fused single-wave, both matmuls inline.
__global__ __launch_bounds__(64, 1)
void gru_fused1(const float* __restrict__ x, const float* __restrict__ h0,
                const float* __restrict__ W, const float* __restrict__ U,
                const float* __restrict__ bi, const float* __restrict__ bh,
                float* __restrict__ out, float* __restrict__ hout)
{
    const int g = blockIdx.x >> 5, b = blockIdx.x & 31;
    const int lane = threadIdx.x;

    float u[64][3], w[64][3];
    {
        const float* Ug = U + (size_t)g * (64 * 192) + lane;
        const float* Wg = W + (size_t)g * (64 * 192) + lane;
        #pragma unroll
        for (int k = 0; k < 64; ++k) {
            u[k][0] = Ug[k * 192]; u[k][1] = Ug[k * 192 + 64]; u[k][2] = Ug[k * 192 + 128];
            w[k][0] = Wg[k * 192]; w[k][1] = Wg[k * 192 + 64]; w[k][2] = Wg[k * 192 + 128];
        }
    }
    #pragma unroll
    for (int k = 0; k < 64; ++k) {
        asm volatile("" : "+v"(u[k][0]), "+v"(u[k][1]), "+v"(u[k][2]));
        asm volatile("" : "+v"(w[k][0]), "+v"(w[k][1]), "+v"(w[k][2]));
    }
    const float biz = bi[g * 192 + lane], bir = bi[g * 192 + 64 + lane], bin_ = bi[g * 192 + 128 + lane];
    const float bhz = bh[g * 192 + lane], bhr = bh[g * 192 + 64 + lane], bhn = bh[g * 192 + 128 + lane];

    float h = h0[(g * 32 + b) * 64 + lane];
    const float* xp = x + (size_t)b * (TS * 512) + g * 64 + lane;
    float xc = xp[0], x1 = xp[512], x2;

    float* op = out + (size_t)b * (TS * 512) + g * 64 + lane;

    for (int t = 0; t < TS; ++t) {
        {
            const int tp = (t + 2 < TS) ? (t + 2) : (TS - 1);
            x2 = xp[(size_t)tp * 512];
        }
        float axz = biz, axr = bir, axn = bin_;
        float ahz = bhz, ahr = bhr, ahn = bhn;
        #pragma unroll
        for (int k = 0; k < 64; ++k) {
            const float sx = rl(xc, k);
            axz = fmaf(sx, w[k][0], axz);
            axr = fmaf(sx, w[k][1], axr);
            axn = fmaf(sx, w[k][2], axn);
        }
        #pragma unroll
        for (int k = 0; k < 64; ++k) {
            const float sh = rl(h, k);
            ahz = fmaf(sh, u[k][0], ahz);
            ahr = fmaf(sh, u[k][1], ahr);
            ahn = fmaf(sh, u[k][2], ahn);
        }
        const float z = fsig(axz + ahz);
        const float r = fsig(axr + ahr);
        const float n = ftanh(fmaf(r, ahn, axn));
        h = n + z * (h - n);
        op[(size_t)t * 512] = h;
        xc = x1; x1 = x2;
    }
    hout[(g * 32 + b) * 64 + lane] = h;
}

extern "C" void kernel_launch(void* const* d_in, const int* in_sizes, int n_in,
                              void* d_out, int out_size, void* d_ws, size_t ws_size,
                              hipStream_t stream) {
    const float* x  = (const float*)d_in[0];
    const float* h0 = (const float*)d_in[1];
    const float* W  = (const float*)d_in[2];
    const float* U  = (const float*)d_in[3];
    const float* bi = (const float*)d_in[4];
    const float* bh = (const float*)d_in[5];
    float* out  = (float*)d_out;
    float* hout = out + (size_t)32 * TS * 512;

    const size_t gx_bytes = (size_t)8 * 32 * TS * 192 * sizeof(float);
    if (ws_size >= gx_bytes) {
        float* gx = (float*)d_ws;
        hipLaunchKernelGGL(gx_gemm, dim3(16, 32, 8), dim3(256), 0, stream, x, W, bi, gx);
        hipLaunchKernelGGL(gru_seq, dim3(256), dim3(64), 0, stream, gx, h0, U, bh, out, hout);
    } else {
        hipLaunchKernelGGL(gru_fused1, dim3(256), dim3(64), 0, stream,
                           x, h0, W, U, bi, bh, out, hout);
    }
}